// Round 2
// baseline (267.361 us; speedup 1.0000x reference)
//
#include <hip/hip_runtime.h>

#define NRES 512
#define CZ   128
#define CT   64

typedef short bf16x8 __attribute__((ext_vector_type(8)));
typedef float f32x4  __attribute__((ext_vector_type(4)));

#define MFMA16(a,b,c) __builtin_amdgcn_mfma_f32_16x16x32_bf16((a),(b),(c),0,0,0)

__device__ __forceinline__ unsigned short f2bf(float f){
  unsigned int u = __builtin_bit_cast(unsigned int, f);
  u += 0x7fffu + ((u >> 16) & 1u);
  return (unsigned short)(u >> 16);
}
__device__ __forceinline__ float bf2f(short b){
  return __builtin_bit_cast(float, ((unsigned int)(unsigned short)b) << 16);
}
__device__ __forceinline__ bf16x8 pack8(const float4 a, const float4 b){
  bf16x8 r;
  r[0]=(short)f2bf(a.x); r[1]=(short)f2bf(a.y); r[2]=(short)f2bf(a.z); r[3]=(short)f2bf(a.w);
  r[4]=(short)f2bf(b.x); r[5]=(short)f2bf(b.y); r[6]=(short)f2bf(b.z); r[7]=(short)f2bf(b.w);
  return r;
}

// ---- weight pre-pack: B-fragments for mfma_f32_16x16x32_bf16 ----
// frag f: lane l, elem j -> B[k = ks*32 + (l>>4)*8 + j][col = nt*16 + (l&15)]
// f  0..15: wq (128x64), nt=f>>2, ks=f&3, scale=0.25 folded in
// f 16..23: wk (64x64),  nt=(f-16)>>1, ks=(f-16)&1
// f 24..31: wv (64x64),  nt=head=(f-24)>>1, ks=(f-24)&1
// f 32..47: wo (64x128), nt=(f-32)>>1, ks=(f-32)&1
__global__ void prep_pack(const float* __restrict__ wq, const float* __restrict__ wk,
                          const float* __restrict__ wv, const float* __restrict__ wo,
                          unsigned short* __restrict__ packed){
  int idx = blockIdx.x * 256 + threadIdx.x;
  if (idx >= 48 * 64) return;
  int f = idx >> 6, lane = idx & 63;
  const float* W; int Ncols, nt, ks; float scale = 1.0f;
  if (f < 16)      { W = wq; Ncols = 64;  nt = f >> 2;        ks = f & 3;        scale = 0.25f; }
  else if (f < 24) { W = wk; Ncols = 64;  nt = (f - 16) >> 1; ks = (f - 16) & 1; }
  else if (f < 32) { W = wv; Ncols = 64;  nt = (f - 24) >> 1; ks = (f - 24) & 1; }
  else             { W = wo; Ncols = 128; nt = (f - 32) >> 1; ks = (f - 32) & 1; }
  int col = nt * 16 + (lane & 15);
  int k0  = ks * 32 + (lane >> 4) * 8;
  unsigned short* dst = packed + (size_t)f * 512 + (size_t)lane * 8;
#pragma unroll
  for (int j = 0; j < 8; ++j)
    dst[j] = f2bf(W[(k0 + j) * Ncols + col] * scale);
}

// LDS (13312 B, ALL wave-private, no __syncthreads in kernel):
//   [0,8192)        o_ws: per-wave 16x64 bf16 O buffer (128B rows, XOR-swizzled)
//   [8192,13312)    a_ws: per-wave 16 (s,h) x 20-float rows of softmax weights
__launch_bounds__(256, 3)
__global__ void tpa_main(const float* __restrict__ t, const float* __restrict__ z,
                         const float* __restrict__ mask, const float* __restrict__ bo,
                         const unsigned short* __restrict__ packed,
                         float* __restrict__ out){
  __shared__ __align__(16) char smem[13312];

  const int tid  = threadIdx.x;
  const int lane = tid & 63;
  const int w    = tid >> 6;         // wave 0..3 -> rows [16w,16w+16) of the 64-tile
  const int cl   = lane & 15;        // A-frag row within 16 / C-frag col
  const int g    = lane >> 4;        // k-subgroup / C-frag row-group
  const int b    = blockIdx.x;
  const int i    = b >> 3;           // z-row
  const int j0   = (b & 7) << 6;     // pixel-column tile base
  const int grow = j0 + (w << 4) + cl;   // global j handled by this lane's A-frag row

  // -------- issue ALL global loads up front (24 x float4 per lane) --------
  const float4* zp = reinterpret_cast<const float4*>(z + ((size_t)i * NRES + grow) * CZ);
  float4 zraw[8];
#pragma unroll
  for (int ks = 0; ks < 4; ++ks)
#pragma unroll
    for (int p = 0; p < 2; ++p)
      zraw[ks * 2 + p] = zp[ks * 8 + g * 2 + p];

  float4 traw[4][4];
#pragma unroll
  for (int s = 0; s < 4; ++s){
    const float4* tp = reinterpret_cast<const float4*>(
        t + (((size_t)s * NRES + i) * NRES + grow) * CT);
#pragma unroll
    for (int ks = 0; ks < 2; ++ks)
#pragma unroll
      for (int p = 0; p < 2; ++p)
        traw[s][ks * 2 + p] = tp[ks * 8 + g * 2 + p];
  }

  float m0 = mask[0], m1 = mask[1], m2 = mask[2], m3 = mask[3];
  float msum = m0 + m1 + m2 + m3;
  float bias[4] = {1e9f * (m0 - 1.0f), 1e9f * (m1 - 1.0f),
                   1e9f * (m2 - 1.0f), 1e9f * (m3 - 1.0f)};

#define LOADB(fi) (*reinterpret_cast<const bf16x8*>(packed + (size_t)(fi) * 512 + (size_t)lane * 8))

  // -------- P1: Q = z-row-frags @ wq (scale folded) --------
  f32x4 qf[4];
  {
    bf16x8 za[4];
#pragma unroll
    for (int ks = 0; ks < 4; ++ks)
      za[ks] = pack8(zraw[ks * 2], zraw[ks * 2 + 1]);
#pragma unroll
    for (int nt = 0; nt < 4; ++nt){
      f32x4 acc = {0.f, 0.f, 0.f, 0.f};
#pragma unroll
      for (int ks = 0; ks < 4; ++ks)
        acc = MFMA16(za[ks], LOADB(nt * 4 + ks), acc);
      qf[nt] = acc;
    }
  }

  // -------- P2: per-template K projection + logits --------
  bf16x8 ta[4][2];           // kept live for P4
#pragma unroll
  for (int s = 0; s < 4; ++s)
#pragma unroll
    for (int ks = 0; ks < 2; ++ks)
      ta[s][ks] = pack8(traw[s][ks * 2], traw[s][ks * 2 + 1]);

  f32x4 lg[4][4];            // [s][head]; rows g*4+r, replicated over 16 lanes of group
#pragma unroll
  for (int s = 0; s < 4; ++s){
#pragma unroll
    for (int nt = 0; nt < 4; ++nt){
      f32x4 acc = {0.f, 0.f, 0.f, 0.f};
      acc = MFMA16(ta[s][0], LOADB(16 + nt * 2 + 0), acc);
      acc = MFMA16(ta[s][1], LOADB(16 + nt * 2 + 1), acc);
      f32x4 p = acc * qf[nt];
#pragma unroll
      for (int off = 1; off < 16; off <<= 1){
#pragma unroll
        for (int r = 0; r < 4; ++r) p[r] += __shfl_xor(p[r], off);
      }
#pragma unroll
      for (int r = 0; r < 4; ++r) p[r] += bias[s];
      lg[s][nt] = p;
    }
  }

  // -------- P3: softmax over s (in place) --------
#pragma unroll
  for (int nt = 0; nt < 4; ++nt){
    f32x4 mx;
#pragma unroll
    for (int r = 0; r < 4; ++r)
      mx[r] = fmaxf(fmaxf(lg[0][nt][r], lg[1][nt][r]), fmaxf(lg[2][nt][r], lg[3][nt][r]));
    f32x4 sum = {0.f, 0.f, 0.f, 0.f};
#pragma unroll
    for (int s = 0; s < 4; ++s){
#pragma unroll
      for (int r = 0; r < 4; ++r) lg[s][nt][r] = __expf(lg[s][nt][r] - mx[r]);
      sum += lg[s][nt];
    }
    f32x4 inv;
#pragma unroll
    for (int r = 0; r < 4; ++r) inv[r] = 1.0f / sum[r];
#pragma unroll
    for (int s = 0; s < 4; ++s) lg[s][nt] *= inv;
  }

  // -------- redistribute a: C-frag rows -> per-lane rows via wave-private LDS --------
  // layout: a_ws[(s*4+h)*20 + local_row]; writer = lane with cl==s*4+h (one per group),
  // writes its group's 4 rows as one ds_write_b128 (4 active lanes, conflict-free).
  float* a_ws = reinterpret_cast<float*>(smem + 8192 + w * 1280);
#pragma unroll
  for (int s = 0; s < 4; ++s)
#pragma unroll
    for (int h = 0; h < 4; ++h)
      if (cl == s * 4 + h)
        *reinterpret_cast<f32x4*>(a_ws + (s * 4 + h) * 20 + (g << 2)) = lg[s][h];
  asm volatile("s_waitcnt lgkmcnt(0)" ::: "memory");

  float as_[4][4];
#pragma unroll
  for (int s = 0; s < 4; ++s)
#pragma unroll
    for (int h = 0; h < 4; ++h)
      as_[s][h] = a_ws[(s * 4 + h) * 20 + cl];   // broadcast reads, 16 banks, free

  // -------- P4: u_h = sum_s a_s * t_s, directly in A-frag layout (registers) --------
  bf16x8 ua[4][2];
#pragma unroll
  for (int h = 0; h < 4; ++h)
#pragma unroll
    for (int ks = 0; ks < 2; ++ks){
      float uu[8];
#pragma unroll
      for (int j = 0; j < 8; ++j)
        uu[j] = as_[0][h] * bf2f(ta[0][ks][j]) + as_[1][h] * bf2f(ta[1][ks][j])
              + as_[2][h] * bf2f(ta[2][ks][j]) + as_[3][h] * bf2f(ta[3][ks][j]);
#pragma unroll
      for (int j = 0; j < 8; ++j) ua[h][ks][j] = (short)f2bf(uu[j]);
    }

  // -------- P5: O[:, h*16:+16] = u_h @ wv_h ; stash O in wave-private swizzled LDS --------
  unsigned short* o_ws = reinterpret_cast<unsigned short*>(smem + w * 2048);
#pragma unroll
  for (int h = 0; h < 4; ++h){
    f32x4 acc = {0.f, 0.f, 0.f, 0.f};
    acc = MFMA16(ua[h][0], LOADB(24 + h * 2 + 0), acc);
    acc = MFMA16(ua[h][1], LOADB(24 + h * 2 + 1), acc);
#pragma unroll
    for (int r = 0; r < 4; ++r){
      int row = (g << 2) + r;
      o_ws[row * 64 + ((h * 16 + cl) ^ ((row & 7) << 3))] = (unsigned short)f2bf(acc[r]);
    }
  }
  asm volatile("s_waitcnt lgkmcnt(0)" ::: "memory");

  // -------- P6: Out = O @ wo + bo, gated; direct f32 stores --------
  {
    bf16x8 oa[2];
#pragma unroll
    for (int ks = 0; ks < 2; ++ks)
      oa[ks] = *reinterpret_cast<const bf16x8*>(
          o_ws + cl * 64 + ((ks * 32 + g * 8) ^ ((cl & 7) << 3)));

    float gate = (msum > 0.0f) ? 1.0f : 0.0f;
    float* outg = out + ((size_t)i * NRES + j0 + (w << 4)) * CZ;
#pragma unroll
    for (int nt = 0; nt < 8; ++nt){
      f32x4 acc = {0.f, 0.f, 0.f, 0.f};
      acc = MFMA16(oa[0], LOADB(32 + nt * 2 + 0), acc);
      acc = MFMA16(oa[1], LOADB(32 + nt * 2 + 1), acc);
      int col = nt * 16 + cl;
      float bov = bo[col];
#pragma unroll
      for (int r = 0; r < 4; ++r)
        outg[(size_t)((g << 2) + r) * CZ + col] = (acc[r] + bov) * gate;
    }
  }
}

extern "C" void kernel_launch(void* const* d_in, const int* in_sizes, int n_in,
                              void* d_out, int out_size, void* d_ws, size_t ws_size,
                              hipStream_t stream) {
  const float* t    = (const float*)d_in[0];
  const float* z    = (const float*)d_in[1];
  const float* mask = (const float*)d_in[2];
  const float* wq   = (const float*)d_in[3];
  const float* wk   = (const float*)d_in[4];
  const float* wv   = (const float*)d_in[5];
  const float* wo   = (const float*)d_in[6];
  const float* bo   = (const float*)d_in[7];
  unsigned short* packed = (unsigned short*)d_ws;

  hipLaunchKernelGGL(prep_pack, dim3(12), dim3(256), 0, stream, wq, wk, wv, wo, packed);
  hipLaunchKernelGGL(tpa_main, dim3(4096), dim3(256), 0, stream,
                     t, z, mask, bo, packed, (float*)d_out);
}

// Round 3
// 127.980 us; speedup vs baseline: 2.0891x; 2.0891x over previous
//
#include <hip/hip_runtime.h>

#define NRES 512
#define CZ   128
#define CT   64

typedef short bf16x8 __attribute__((ext_vector_type(8)));
typedef float f32x4  __attribute__((ext_vector_type(4)));

#define MFMA16(a,b,c) __builtin_amdgcn_mfma_f32_16x16x32_bf16((a),(b),(c),0,0,0)

__device__ __forceinline__ unsigned short f2bf(float f){
  unsigned int u = __builtin_bit_cast(unsigned int, f);
  u += 0x7fffu + ((u >> 16) & 1u);
  return (unsigned short)(u >> 16);
}
__device__ __forceinline__ float bf2f(short b){
  return __builtin_bit_cast(float, ((unsigned int)(unsigned short)b) << 16);
}
__device__ __forceinline__ bf16x8 pack8(const float4 a, const float4 b){
  bf16x8 r;
  r[0]=(short)f2bf(a.x); r[1]=(short)f2bf(a.y); r[2]=(short)f2bf(a.z); r[3]=(short)f2bf(a.w);
  r[4]=(short)f2bf(b.x); r[5]=(short)f2bf(b.y); r[6]=(short)f2bf(b.z); r[7]=(short)f2bf(b.w);
  return r;
}

// ---- weight pre-pack: B-fragments for mfma_f32_16x16x32_bf16 ----
// frag f: lane l, elem j -> B[k = ks*32 + (l>>4)*8 + j][col = nt*16 + (l&15)]
// f  0..15: wq (128x64), nt=f>>2, ks=f&3, scale=0.25 folded in
// f 16..23: wk (64x64),  nt=(f-16)>>1, ks=(f-16)&1
// f 24..31: wv (64x64),  nt=head=(f-24)>>1, ks=(f-24)&1
// f 32..47: wo (64x128), nt=(f-32)>>1, ks=(f-32)&1
__global__ void prep_pack(const float* __restrict__ wq, const float* __restrict__ wk,
                          const float* __restrict__ wv, const float* __restrict__ wo,
                          unsigned short* __restrict__ packed){
  int idx = blockIdx.x * 256 + threadIdx.x;
  if (idx >= 48 * 64) return;
  int f = idx >> 6, lane = idx & 63;
  const float* W; int Ncols, nt, ks; float scale = 1.0f;
  if (f < 16)      { W = wq; Ncols = 64;  nt = f >> 2;        ks = f & 3;        scale = 0.25f; }
  else if (f < 24) { W = wk; Ncols = 64;  nt = (f - 16) >> 1; ks = (f - 16) & 1; }
  else if (f < 32) { W = wv; Ncols = 64;  nt = (f - 24) >> 1; ks = (f - 24) & 1; }
  else             { W = wo; Ncols = 128; nt = (f - 32) >> 1; ks = (f - 32) & 1; }
  int col = nt * 16 + (lane & 15);
  int k0  = ks * 32 + (lane >> 4) * 8;
  unsigned short* dst = packed + (size_t)f * 512 + (size_t)lane * 8;
#pragma unroll
  for (int j = 0; j < 8; ++j)
    dst[j] = f2bf(W[(k0 + j) * Ncols + col] * scale);
}

// LDS (37888 B, ALL wave-private, zero __syncthreads):
//  [0,32768)      Tb: wave w, templ s at (w*4+s)*2048: 16 rows x 64 bf16,
//                 128B rows, byte-swizzle ^((row&7)<<4).
//                 After P2 frag reads, slot s=0 of each wave is reused for O.
//  [32768,37888)  a_ws: per wave 1280B = 16 (s,h) x 20-float rows
__launch_bounds__(256, 3)
__global__ void tpa_main(const float* __restrict__ t, const float* __restrict__ z,
                         const float* __restrict__ mask, const float* __restrict__ bo,
                         const unsigned short* __restrict__ packed,
                         float* __restrict__ out){
  __shared__ __align__(16) char smem[37888];

  const int tid  = threadIdx.x;
  const int lane = tid & 63;
  const int w    = tid >> 6;         // wave 0..3 -> rows [16w,16w+16) of the 64-pixel tile
  const int cl   = lane & 15;        // A-frag row within 16 / C-frag col
  const int g    = lane >> 4;        // k-subgroup / C-frag row-group
  const int b    = blockIdx.x;
  const int i    = b >> 3;           // z-row
  const int j0   = (b & 7) << 6;     // pixel-column tile base
  const int r0   = j0 + (w << 4);    // wave's first global pixel row
  const int grow = r0 + cl;          // this lane's A-frag global row

  // -------- issue z fragment loads first (in flight during t staging) --------
  const float4* zp = reinterpret_cast<const float4*>(z + ((size_t)i * NRES + grow) * CZ);
  float4 zr[8];
#pragma unroll
  for (int ks = 0; ks < 4; ++ks)
#pragma unroll
    for (int p = 0; p < 2; ++p)
      zr[ks * 2 + p] = zp[ks * 8 + g * 2 + p];

  // -------- stage t wave-privately: 4 x (16 rows x 64 f32) -> bf16 LDS --------
  // dense: each inner instr is 64 lanes x 16B = 1KB contiguous
#pragma unroll
  for (int s = 0; s < 4; ++s){
    const float4* tp4 = reinterpret_cast<const float4*>(
        t + (((size_t)s * NRES + i) * NRES + r0) * CT);
    char* tb = smem + (w * 4 + s) * 2048;
#pragma unroll
    for (int it = 0; it < 4; ++it){
      int idx = it * 64 + lane;
      float4 v = tp4[idx];
      int row = idx >> 4, c4 = idx & 15;
      unsigned int lo = (unsigned int)f2bf(v.x) | ((unsigned int)f2bf(v.y) << 16);
      unsigned int hi = (unsigned int)f2bf(v.z) | ((unsigned int)f2bf(v.w) << 16);
      *reinterpret_cast<uint2*>(tb + row * 128 + ((c4 * 8) ^ ((row & 7) << 4))) =
          make_uint2(lo, hi);
    }
  }

  // -------- convert z to A-frags, free raw --------
  bf16x8 za[4];
#pragma unroll
  for (int ks = 0; ks < 4; ++ks) za[ks] = pack8(zr[ks * 2], zr[ks * 2 + 1]);

  float m0 = mask[0], m1 = mask[1], m2 = mask[2], m3 = mask[3];
  float msum = m0 + m1 + m2 + m3;
  float bias[4] = {1e9f * (m0 - 1.0f), 1e9f * (m1 - 1.0f),
                   1e9f * (m2 - 1.0f), 1e9f * (m3 - 1.0f)};

  // -------- read back t A-frags (held for P2 and P4) --------
  bf16x8 ta[4][2];
#pragma unroll
  for (int s = 0; s < 4; ++s){
    const char* tb = smem + (w * 4 + s) * 2048;
#pragma unroll
    for (int ks = 0; ks < 2; ++ks)
      ta[s][ks] = *reinterpret_cast<const bf16x8*>(
          tb + cl * 128 + ((ks * 64 + g * 16) ^ ((cl & 7) << 4)));
  }

#define LOADB(fi) (*reinterpret_cast<const bf16x8*>(packed + (size_t)(fi) * 512 + (size_t)lane * 8))

  float* a_ws = reinterpret_cast<float*>(smem + 32768 + w * 1280);

  // -------- per-head: Q proj, K proj, logits, softmax, a -> LDS --------
#pragma unroll
  for (int h = 0; h < 4; ++h){
    f32x4 q = {0.f, 0.f, 0.f, 0.f};
#pragma unroll
    for (int ks = 0; ks < 4; ++ks) q = MFMA16(za[ks], LOADB(h * 4 + ks), q);

    f32x4 lgh[4];
#pragma unroll
    for (int s = 0; s < 4; ++s){
      f32x4 acc = {0.f, 0.f, 0.f, 0.f};
      acc = MFMA16(ta[s][0], LOADB(16 + h * 2 + 0), acc);
      acc = MFMA16(ta[s][1], LOADB(16 + h * 2 + 1), acc);
      f32x4 p = acc * q;
#pragma unroll
      for (int off = 1; off < 16; off <<= 1){
#pragma unroll
        for (int r = 0; r < 4; ++r) p[r] += __shfl_xor(p[r], off);
      }
#pragma unroll
      for (int r = 0; r < 4; ++r) p[r] += bias[s];
      lgh[s] = p;
    }
    // softmax over s
    f32x4 mx, sum = {0.f, 0.f, 0.f, 0.f};
#pragma unroll
    for (int r = 0; r < 4; ++r)
      mx[r] = fmaxf(fmaxf(lgh[0][r], lgh[1][r]), fmaxf(lgh[2][r], lgh[3][r]));
#pragma unroll
    for (int s = 0; s < 4; ++s){
#pragma unroll
      for (int r = 0; r < 4; ++r) lgh[s][r] = __expf(lgh[s][r] - mx[r]);
      sum += lgh[s];
    }
    f32x4 inv;
#pragma unroll
    for (int r = 0; r < 4; ++r) inv[r] = 1.0f / sum[r];
#pragma unroll
    for (int s = 0; s < 4; ++s){
      lgh[s] *= inv;
      if (cl == s * 4 + h)
        *reinterpret_cast<f32x4*>(a_ws + (s * 4 + h) * 20 + (g << 2)) = lgh[s];
    }
  }
  asm volatile("s_waitcnt lgkmcnt(0)" ::: "memory");

  // -------- per-head: u = sum_s a_s*t_s (A-frag regs), V proj, O -> LDS --------
  unsigned short* o_ws = reinterpret_cast<unsigned short*>(smem + w * 8192); // Tb slot s=0, now dead
#pragma unroll
  for (int h = 0; h < 4; ++h){
    float a0 = a_ws[(0  + h) * 20 + cl];
    float a1 = a_ws[(4  + h) * 20 + cl];
    float a2 = a_ws[(8  + h) * 20 + cl];
    float a3 = a_ws[(12 + h) * 20 + cl];
    bf16x8 ua[2];
#pragma unroll
    for (int ks = 0; ks < 2; ++ks){
#pragma unroll
      for (int j = 0; j < 8; ++j){
        float uu = a0 * bf2f(ta[0][ks][j]) + a1 * bf2f(ta[1][ks][j])
                 + a2 * bf2f(ta[2][ks][j]) + a3 * bf2f(ta[3][ks][j]);
        ua[ks][j] = (short)f2bf(uu);
      }
    }
    f32x4 acc = {0.f, 0.f, 0.f, 0.f};
    acc = MFMA16(ua[0], LOADB(24 + h * 2 + 0), acc);
    acc = MFMA16(ua[1], LOADB(24 + h * 2 + 1), acc);
#pragma unroll
    for (int r = 0; r < 4; ++r){
      int row = (g << 2) + r;
      o_ws[row * 64 + ((h * 16 + cl) ^ ((row & 7) << 3))] = (unsigned short)f2bf(acc[r]);
    }
  }
  asm volatile("s_waitcnt lgkmcnt(0)" ::: "memory");

  // -------- out = O @ wo + bo, gated; direct f32 stores --------
  {
    bf16x8 oa[2];
#pragma unroll
    for (int ks = 0; ks < 2; ++ks)
      oa[ks] = *reinterpret_cast<const bf16x8*>(
          o_ws + cl * 64 + ((ks * 32 + g * 8) ^ ((cl & 7) << 3)));

    float gate = (msum > 0.0f) ? 1.0f : 0.0f;
    float* outg = out + ((size_t)i * NRES + r0) * CZ;
#pragma unroll
    for (int nt = 0; nt < 8; ++nt){
      f32x4 acc = {0.f, 0.f, 0.f, 0.f};
      acc = MFMA16(oa[0], LOADB(32 + nt * 2 + 0), acc);
      acc = MFMA16(oa[1], LOADB(32 + nt * 2 + 1), acc);
      int col = nt * 16 + cl;
      float bov = bo[col];
#pragma unroll
      for (int r = 0; r < 4; ++r)
        outg[(size_t)((g << 2) + r) * CZ + col] = (acc[r] + bov) * gate;
    }
  }
}

extern "C" void kernel_launch(void* const* d_in, const int* in_sizes, int n_in,
                              void* d_out, int out_size, void* d_ws, size_t ws_size,
                              hipStream_t stream) {
  const float* t    = (const float*)d_in[0];
  const float* z    = (const float*)d_in[1];
  const float* mask = (const float*)d_in[2];
  const float* wq   = (const float*)d_in[3];
  const float* wk   = (const float*)d_in[4];
  const float* wv   = (const float*)d_in[5];
  const float* wo   = (const float*)d_in[6];
  const float* bo   = (const float*)d_in[7];
  unsigned short* packed = (unsigned short*)d_ws;

  hipLaunchKernelGGL(prep_pack, dim3(12), dim3(256), 0, stream, wq, wk, wv, wo, packed);
  hipLaunchKernelGGL(tpa_main, dim3(4096), dim3(256), 0, stream,
                     t, z, mask, bo, packed, (float*)d_out);
}